// Round 1
// baseline (912.201 us; speedup 1.0000x reference)
//
#include <hip/hip_runtime.h>

// Problem constants
static constexpr int Nn_ = 32, Cc_ = 64, Hh_ = 64, Ww_ = 64;
static constexpr int K_ = 512;
static constexpr int T_ = Nn_ * Hh_ * Ww_;        // 131072 tokens
static constexpr int OUT_ELEMS = Nn_ * Cc_ * Hh_ * Ww_;  // 8388608
// d_out layout: [out (8388608)] [codebook_new (32768)] [N_new (512)] [m_new (32768)]
static constexpr int OFF_CB = OUT_ELEMS;
static constexpr int OFF_N  = OUT_ELEMS + 32768;
static constexpr int OFF_M  = OUT_ELEMS + 32768 + 512;

// ws float layout: [0,512) cnorm2 | [512,1024) counts | [1024, 1024+32768) sums
static constexpr int WS_CNORM = 0;
static constexpr int WS_CNT   = 512;
static constexpr int WS_SUM   = 1024;
static constexpr int WS_TOTAL = 1024 + K_ * Cc_;  // 33792 floats

// K0: compute |c|^2 per codeword, zero counts+sums
__global__ __launch_bounds__(256) void k_prep(const float* __restrict__ cb,
                                              float* __restrict__ ws) {
    int i = blockIdx.x * 256 + threadIdx.x;
    if (i < 512) {
        const float* r = cb + i * 64;
        float a = 0.f;
#pragma unroll
        for (int j = 0; j < 64; ++j) a = fmaf(r[j], r[j], a);
        ws[WS_CNORM + i] = a;
    } else if (i < WS_TOTAL) {
        ws[i] = 0.f;   // covers counts + sums
    }
}

// K1: per-token argmin over 512 codewords, write q to out, accumulate counts/sums
__global__ __launch_bounds__(256) void k_assign(const float* __restrict__ x,
                                                const float* __restrict__ cb,
                                                float* ws,
                                                float* __restrict__ out) {
    const float* cnorm2 = ws + WS_CNORM;
    float* counts = ws + WS_CNT;
    float* sums   = ws + WS_SUM;

    int tid  = blockIdx.x * 256 + threadIdx.x;
    int wave = tid >> 6;          // 0..2047  == n*64 + h
    int lane = tid & 63;          // == w coordinate
    int n = wave >> 6;
    int h = wave & 63;
    // x[n][c][h][w] flat index: n*C*H*W + c*H*W + h*W + w
    int base = n * (Cc_ * Hh_ * Ww_) + h * Ww_ + lane;

    // Load this token's 64 channels (each load coalesced across the wave)
    float xr[64];
#pragma unroll
    for (int c = 0; c < 64; ++c) xr[c] = x[base + c * (Hh_ * Ww_)];

    float xn = 0.f;
#pragma unroll
    for (int c = 0; c < 64; ++c) xn = fmaf(xr[c], xr[c], xn);

    float best = __builtin_inff();
    int bidx = 0;
    for (int k = 0; k < K_; ++k) {
        const float* __restrict__ cr = cb + k * 64;  // wave-uniform -> s_load
        float acc = 0.f;
#pragma unroll
        for (int j = 0; j < 64; ++j) acc = fmaf(xr[j], cr[j], acc);
        float d2 = (xn - 2.0f * acc) + cnorm2[k];
        if (d2 < best) { best = d2; bidx = k; }   // strict < -> first-min like np.argmin
    }

    atomicAdd(&counts[bidx], 1.0f);

    const float* __restrict__ qrow = cb + bidx * 64;  // per-lane gather (L2-hot)
#pragma unroll
    for (int c = 0; c < 64; ++c) {
        out[base + c * (Hh_ * Ww_)] = qrow[c];        // coalesced store per channel
        atomicAdd(&sums[bidx * 64 + c], xr[c]);
    }
}

// K2: finalize EMA states and codebook_new
__global__ __launch_bounds__(256) void k_final(const float* __restrict__ Ns,
                                               const float* __restrict__ ms,
                                               const float* __restrict__ ws,
                                               float* __restrict__ out) {
    const float* counts = ws + WS_CNT;
    const float* sums   = ws + WS_SUM;
    int i = blockIdx.x * 256 + threadIdx.x;  // 0..32767  (k*64 + c)
    int k = i >> 6;

    const float gamma = 0.99f;
    const float omg   = (float)(1.0 - 0.99);  // match python double->f32

    float cnt = counts[k];
    bool occ = cnt > 0.0f;

    float Nv = Ns[k];
    float Nnew = occ ? (Nv * gamma + cnt * omg) : Nv;

    float mv = ms[i];
    float mnew = occ ? (mv * gamma + sums[i] * omg) : mv;

    out[OFF_CB + i] = mnew / Nnew;
    out[OFF_M  + i] = mnew;
    if ((i & 63) == 0) out[OFF_N + k] = Nnew;
}

extern "C" void kernel_launch(void* const* d_in, const int* in_sizes, int n_in,
                              void* d_out, int out_size, void* d_ws, size_t ws_size,
                              hipStream_t stream) {
    const float* x  = (const float*)d_in[0];
    const float* cb = (const float*)d_in[1];
    const float* Ns = (const float*)d_in[2];
    const float* ms = (const float*)d_in[3];
    float* out = (float*)d_out;
    float* ws  = (float*)d_ws;

    // K0: 33792 floats to touch -> 132 blocks
    hipLaunchKernelGGL(k_prep, dim3((WS_TOTAL + 255) / 256), dim3(256), 0, stream, cb, ws);
    // K1: one wave per (n,h) row: 2048 waves = 512 blocks of 256
    hipLaunchKernelGGL(k_assign, dim3(T_ / 256), dim3(256), 0, stream, x, cb, ws, out);
    // K2: 32768 threads
    hipLaunchKernelGGL(k_final, dim3(32768 / 256), dim3(256), 0, stream, Ns, ms, ws, out);
}

// Round 2
// 472.545 us; speedup vs baseline: 1.9304x; 1.9304x over previous
//
#include <hip/hip_runtime.h>

// Problem constants
static constexpr int Nn_ = 32, Cc_ = 64, Hh_ = 64, Ww_ = 64;
static constexpr int K_ = 512;
static constexpr int HW_ = Hh_ * Ww_;             // 4096
static constexpr int CHW_ = Cc_ * HW_;            // 262144
static constexpr int T_ = Nn_ * Hh_ * Ww_;        // 131072 tokens
static constexpr int OUT_ELEMS = Nn_ * Cc_ * Hh_ * Ww_;  // 8388608
// d_out layout: [out (8388608)] [codebook_new (32768)] [N_new (512)] [m_new (32768)]
static constexpr int OFF_CB = OUT_ELEMS;
static constexpr int OFF_N  = OUT_ELEMS + 32768;
static constexpr int OFF_M  = OUT_ELEMS + 32768 + 512;

// ws layout (4-byte units):
// [0, 131072)          idx per token (int)
// [131072, 131584)     cnorm2 (float)
// [131584, 132096)     counts (float)
// [132096, 164864)     sums [512][64] (float)
static constexpr int WS_IDX   = 0;
static constexpr int WS_CNORM = T_;
static constexpr int WS_CNT   = T_ + 512;
static constexpr int WS_SUM   = T_ + 1024;

// K0: |c|^2 per codeword
__global__ __launch_bounds__(256) void k_prep(const float* __restrict__ cb,
                                              float* __restrict__ ws) {
    int i = blockIdx.x * 256 + threadIdx.x;
    if (i < K_) {
        const float* r = cb + i * 64;
        float a = 0.f;
#pragma unroll
        for (int j = 0; j < 64; ++j) a = fmaf(r[j], r[j], a);
        ws[WS_CNORM + i] = a;
    }
}

// K1: per-token argmin over 512 codewords, write q to out, write index. NO atomics.
__global__ __launch_bounds__(256) void k_assign(const float* __restrict__ x,
                                                const float* __restrict__ cb,
                                                float* __restrict__ ws,
                                                float* __restrict__ out) {
    const float* cnorm2 = ws + WS_CNORM;
    int* idx_out = (int*)(ws + WS_IDX);

    int tid  = blockIdx.x * 256 + threadIdx.x;
    int wave = tid >> 6;          // n*64 + h
    int lane = tid & 63;          // w
    int n = wave >> 6;
    int h = wave & 63;
    int base = n * CHW_ + h * Ww_ + lane;   // x[n][.][h][w]

    // 64 channels, each load coalesced across the wave
    float xr[64];
#pragma unroll
    for (int c = 0; c < 64; ++c) xr[c] = x[base + c * HW_];

    float xn = 0.f;
#pragma unroll
    for (int c = 0; c < 64; ++c) xn = fmaf(xr[c], xr[c], xn);

    float best = __builtin_inff();
    int bidx = 0;
    for (int k = 0; k < K_; ++k) {
        const float* __restrict__ cr = cb + k * 64;  // wave-uniform -> s_load
        float acc = 0.f;
#pragma unroll
        for (int j = 0; j < 64; ++j) acc = fmaf(xr[j], cr[j], acc);
        float d2 = (xn - 2.0f * acc) + cnorm2[k];
        if (d2 < best) { best = d2; bidx = k; }   // strict < == np.argmin first-min
    }

    idx_out[tid] = bidx;   // coalesced

    const float* __restrict__ qrow = cb + bidx * 64;  // L2-hot gather
#pragma unroll
    for (int c = 0; c < 64; ++c) {
        out[base + c * HW_] = qrow[c];                // coalesced store per channel
    }
}

// K2: segment-sum, one block per codeword, no atomics (except LDS list append).
static constexpr int CHUNK = 8192;
__global__ __launch_bounds__(256) void k_stats(const float* __restrict__ x,
                                               const float* __restrict__ ws_ro,
                                               float* __restrict__ ws) {
    const int* __restrict__ idx = (const int*)(ws_ro + WS_IDX);
    float* counts = ws + WS_CNT;
    float* sums   = ws + WS_SUM;

    __shared__ int list[CHUNK];
    __shared__ int cnt;
    __shared__ float partial[4][64];

    const int k = blockIdx.x;
    const int tid = threadIdx.x;
    const int c = tid & 63;        // channel owned by this thread
    const int p = tid >> 6;        // part 0..3

    float acc = 0.f;
    int total = 0;

    for (int cs = 0; cs < T_; cs += CHUNK) {
        if (tid == 0) cnt = 0;
        __syncthreads();           // also guards list reuse vs previous phase2
        // phase 1: scan indices (coalesced; idx array is L2-resident)
        for (int t = cs + tid; t < cs + CHUNK; t += 256) {
            if (idx[t] == k) {
                int pos = atomicAdd(&cnt, 1);   // LDS atomic
                list[pos] = t;
            }
        }
        __syncthreads();
        int M = cnt;
        total += M;
        // phase 2: channel-parallel gather-accumulate
        for (int j = p; j < M; j += 4) {
            int t = list[j];
            int n = t >> 12;
            int hw = t & 4095;
            acc += x[n * CHW_ + c * HW_ + hw];
        }
    }

    partial[p][c] = acc;
    __syncthreads();
    if (tid < 64) {
        float s = partial[0][c] + partial[1][c] + partial[2][c] + partial[3][c];
        sums[k * 64 + c] = s;
        if (c == 0) counts[k] = (float)total;
    }
}

// K3: finalize EMA states and codebook_new
__global__ __launch_bounds__(256) void k_final(const float* __restrict__ Ns,
                                               const float* __restrict__ ms,
                                               const float* __restrict__ ws,
                                               float* __restrict__ out) {
    const float* counts = ws + WS_CNT;
    const float* sums   = ws + WS_SUM;
    int i = blockIdx.x * 256 + threadIdx.x;  // k*64 + c
    int k = i >> 6;

    const float gamma = 0.99f;
    const float omg   = (float)(1.0 - 0.99);

    float cnt = counts[k];
    bool occ = cnt > 0.0f;

    float Nv = Ns[k];
    float Nnew = occ ? (Nv * gamma + cnt * omg) : Nv;

    float mv = ms[i];
    float mnew = occ ? (mv * gamma + sums[i] * omg) : mv;

    out[OFF_CB + i] = mnew / Nnew;
    out[OFF_M  + i] = mnew;
    if ((i & 63) == 0) out[OFF_N + k] = Nnew;
}

extern "C" void kernel_launch(void* const* d_in, const int* in_sizes, int n_in,
                              void* d_out, int out_size, void* d_ws, size_t ws_size,
                              hipStream_t stream) {
    const float* x  = (const float*)d_in[0];
    const float* cb = (const float*)d_in[1];
    const float* Ns = (const float*)d_in[2];
    const float* ms = (const float*)d_in[3];
    float* out = (float*)d_out;
    float* ws  = (float*)d_ws;

    hipLaunchKernelGGL(k_prep,   dim3(2),        dim3(256), 0, stream, cb, ws);
    hipLaunchKernelGGL(k_assign, dim3(T_ / 256), dim3(256), 0, stream, x, cb, ws, out);
    hipLaunchKernelGGL(k_stats,  dim3(K_),       dim3(256), 0, stream, x, ws, ws);
    hipLaunchKernelGGL(k_final,  dim3(32768 / 256), dim3(256), 0, stream, Ns, ms, ws, out);
}